// Round 9
// baseline (4492.713 us; speedup 1.0000x reference)
//
#include <hip/hip_runtime.h>

// R19 = R18 resubmitted verbatim (R8 bench was an infra failure: container
// acquire failed twice; kernel never ran, no counters, no theory update).
// R18: wave-role split (MFMA waves ∥ VALU waves) to halve matrix-pipe time.
// R17 (3170us, 928cy/step) breakdown: ~120 read-lat + ~264 MATRIX-PIPE
// (128 MFMA/CU/layer is the matvec floor; M-waste irreducible) + ~80
// tail/barrier. More MFMA waves can't reduce the 264. The idle VALU can:
// m114 says MFMA-wave + VALU-wave on one SIMD co-issue (max, not sum), and
// VALU-fdot2 matvec rate ~= matrix-pipe matvec rate here (~1 cy/col/SIMD).
// R13's in-wave hybrid failed (serial issue); role-per-wave fixes that.
//  - waves g=0..3 (SIMD g): MFMA role, cols [64g,64g+32): 2 tiles, 16 MFMA
//    (R17's validated LAYER, tile base 64g).
//  - waves g=4..7 (SIMD g-4): VALU role, cols [64(g-4)+32,+32): R13's
//    validated fdot2 path verbatim (2 lanes/col, K-half p=q>>1, 64 fdot2,
//    shfl_xor(32) partner sum).
//  - projection/staging unchanged (wave g projects pchunk[.][g] = cols
//    [32g,32g+32)); steady remap: MFMA wave reads pchunk[.][2g], VALU wave
//    pchunk[.][2(g&3)+1]. mycol = 64(g&3)+((g>>2)<<5)+((q&1)<<4)+n.
//  - keeps: L==2 static addressing, PRE=2*log2e prescale, shared-zero C-in,
//    exp2/rcp tail (all validated, absmax 0.0039).
// 64 WGs (1/CU) x 512 thr (8 waves, 2/SIMD).

typedef _Float16 half8 __attribute__((ext_vector_type(8)));
typedef _Float16 h2    __attribute__((ext_vector_type(2)));
typedef float    f32x4 __attribute__((ext_vector_type(4)));

union H8u { half8 v; h2 p[4]; };

#define LGKM_BARRIER() asm volatile("s_waitcnt lgkmcnt(0)\n\ts_barrier" ::: "memory")

__device__ __forceinline__ half8 cvt8s(float4 v0, float4 v1, float s) {
    half8 hv;
    hv[0]=(_Float16)(v0.x*s); hv[1]=(_Float16)(v0.y*s);
    hv[2]=(_Float16)(v0.z*s); hv[3]=(_Float16)(v0.w*s);
    hv[4]=(_Float16)(v1.x*s); hv[5]=(_Float16)(v1.y*s);
    hv[6]=(_Float16)(v1.z*s); hv[7]=(_Float16)(v1.w*s);
    return hv;
}
__device__ __forceinline__ half8 cvt8(float4 v0, float4 v1) {
    half8 hv;
    hv[0]=(_Float16)v0.x; hv[1]=(_Float16)v0.y;
    hv[2]=(_Float16)v0.z; hv[3]=(_Float16)v0.w;
    hv[4]=(_Float16)v1.x; hv[5]=(_Float16)v1.y;
    hv[6]=(_Float16)v1.z; hv[7]=(_Float16)v1.w;
    return hv;
}

__global__ void __launch_bounds__(512, 2)
ltc_fused(const float* __restrict__ x,      // [B,T,128]
          const float* __restrict__ W_in,   // [256,128]
          const float* __restrict__ b_in,   // [256]
          const float* __restrict__ W_rec,  // [256,256]
          const float* __restrict__ b_rec,  // [256]
          const float* __restrict__ tau,    // [256]
          const int*   __restrict__ num_layers,
          float*       __restrict__ out,    // [B,256]
          int T)
{
    const int b    = blockIdx.x;
    const int tid  = threadIdx.x;
    const int lane = tid & 63;
    const int g    = tid >> 6;             // wave 0..7
    const int n    = lane & 15;
    const int q    = lane >> 4;
    const int t_my = q & 1;
    const int p    = q >> 1;               // K-half (VALU role)
    const bool mfma_role = (g < 4);
    const int L    = num_layers[0];
    // steady-loop owned column (both roles):
    const int mycol = 64*(g & 3) + ((g >> 2) << 5) + (t_my << 4) + n;
    const int pg    = mfma_role ? 2*g : 2*(g & 3) + 1;   // pchunk wave slot
    const unsigned shamt = (unsigned)(t_my << 4);

    __shared__ _Float16 hbuf[2][256];           // h, PLAIN layout, dbuf
    __shared__ _Float16 xstage[2][16][16][8];   // x chunk, A-frag order
    __shared__ _Float16 pchunk[32][8][16][2];   // proj chunk [ts][g][n][t]

    const float PRE = 2.8853900817779268f;      // 2*log2(e)

    // ---- role weights ----
    half8 bh[2][8];      // MFMA role: W_rec tiles at cols 64g+16t+n
    h2    wv[64];        // VALU role: W_rec row mycol, K-half p
    if (mfma_role) {
#pragma unroll
        for (int t = 0; t < 2; ++t) {
            const int col = 64*g + 16*t + n;
            const float* rp = &W_rec[col * 256 + 8*q];
#pragma unroll
            for (int i = 0; i < 8; ++i)
                bh[t][i] = cvt8s(*(const float4*)&rp[32*i],
                                 *(const float4*)&rp[32*i + 4], PRE);
        }
    } else {
        const float* wp = &W_rec[mycol * 256 + 128*p];
#pragma unroll
        for (int j = 0; j < 32; ++j) {
            float4 w4 = *(const float4*)&wp[4*j];
            h2 a;  a[0]  = (_Float16)(w4.x * PRE); a[1]  = (_Float16)(w4.y * PRE);
            h2 c2; c2[0] = (_Float16)(w4.z * PRE); c2[1] = (_Float16)(w4.w * PRE);
            wv[2*j]   = a;
            wv[2*j+1] = c2;
        }
    }
    // ---- projection B-frags + bias: tied to PROJECTION cols [32g,32g+32) ----
    half8 bx[2][4];
    float biasv[2];
#pragma unroll
    for (int t = 0; t < 2; ++t) {
        const int col = 32*g + 16*t + n;
        const float* ip = &W_in[col * 128 + 8*q];
#pragma unroll
        for (int i = 0; i < 4; ++i)
            bx[t][i] = cvt8s(*(const float4*)&ip[32*i],
                             *(const float4*)&ip[32*i + 4], PRE);
        biasv[t] = (b_in[col] + b_rec[col]) * PRE;
    }
    const float sj   = 0.1f / fminf(fmaxf(tau[mycol], 0.1f), 5.0f);
    const float nsj2 = -2.0f * sj;
    float hj = 0.0f;

    if (tid < 256) hbuf[0][tid] = (_Float16)0.0f;   // zero h buffer 0

    const float* xb  = x + (size_t)b * T * 128;
    const int    t_u = tid >> 4;           // staging: timestep in chunk 0..31
    const int    c16 = tid & 15;           // staging: 8-f32 kblock index
    const int    Mts = t_u >> 4, ms = t_u & 15;

    float4 xpreA, xpreB;
    {
        int tg = t_u; if (tg > T - 1) tg = T - 1;
        const float4* src = (const float4*)(xb + (size_t)tg * 128 + 8*c16);
        xpreA = src[0]; xpreB = src[1];
    }

// one recurrent layer: read hbuf[RB] (static), write hbuf[WB] (static)
#define LAYER(RB, WB, XCQ)                                                   \
    do {                                                                     \
        float z;                                                             \
        if (mfma_role) {                                                     \
            half8 ah[8];                                                     \
            _Pragma("unroll")                                                \
            for (int i = 0; i < 8; ++i)                                      \
                ah[i] = *(const half8*)&hbuf[RB][32*i + 8*q];                \
            const f32x4 zz = (f32x4){0.f, 0.f, 0.f, 0.f};                    \
            f32x4 A0[2], A1[2], A2[2], A3[2];                                \
            _Pragma("unroll")                                                \
            for (int t = 0; t < 2; ++t) {                                    \
                A0[t] = __builtin_amdgcn_mfma_f32_16x16x32_f16(              \
                    ah[0], bh[t][0], zz, 0, 0, 0);                           \
                A1[t] = __builtin_amdgcn_mfma_f32_16x16x32_f16(              \
                    ah[2], bh[t][2], zz, 0, 0, 0);                           \
                A2[t] = __builtin_amdgcn_mfma_f32_16x16x32_f16(              \
                    ah[4], bh[t][4], zz, 0, 0, 0);                           \
                A3[t] = __builtin_amdgcn_mfma_f32_16x16x32_f16(              \
                    ah[6], bh[t][6], zz, 0, 0, 0);                           \
            }                                                                \
            _Pragma("unroll")                                                \
            for (int t = 0; t < 2; ++t) {                                    \
                A0[t] = __builtin_amdgcn_mfma_f32_16x16x32_f16(              \
                    ah[1], bh[t][1], A0[t], 0, 0, 0);                        \
                A1[t] = __builtin_amdgcn_mfma_f32_16x16x32_f16(              \
                    ah[3], bh[t][3], A1[t], 0, 0, 0);                        \
                A2[t] = __builtin_amdgcn_mfma_f32_16x16x32_f16(              \
                    ah[5], bh[t][5], A2[t], 0, 0, 0);                        \
                A3[t] = __builtin_amdgcn_mfma_f32_16x16x32_f16(              \
                    ah[7], bh[t][7], A3[t], 0, 0, 0);                        \
            }                                                                \
            float s0 = t_my ? A0[1][0] : A0[0][0];                           \
            float s1 = t_my ? A1[1][0] : A1[0][0];                           \
            float s2 = t_my ? A2[1][0] : A2[0][0];                           \
            float s3 = t_my ? A3[1][0] : A3[0][0];                           \
            z = ((s0 + s1) + (s2 + s3)) + (XCQ);                             \
        } else {                                                             \
            H8u hp[16];                                                      \
            _Pragma("unroll")                                                \
            for (int j = 0; j < 16; ++j)                                     \
                hp[j].v = *(const half8*)&hbuf[RB][128*p + 8*j];             \
            float acc0 = 0.f, acc1 = 0.f, acc2 = 0.f, acc3 = 0.f;            \
            _Pragma("unroll")                                                \
            for (int j = 0; j < 16; j += 4) {                                \
                _Pragma("unroll")                                            \
                for (int u = 0; u < 4; ++u) {                                \
                    acc0 = __builtin_amdgcn_fdot2(hp[j  ].p[u], wv[4*j    +u], acc0, false); \
                    acc1 = __builtin_amdgcn_fdot2(hp[j+1].p[u], wv[4*(j+1)+u], acc1, false); \
                    acc2 = __builtin_amdgcn_fdot2(hp[j+2].p[u], wv[4*(j+2)+u], acc2, false); \
                    acc3 = __builtin_amdgcn_fdot2(hp[j+3].p[u], wv[4*(j+3)+u], acc3, false); \
                }                                                            \
            }                                                                \
            float sv = (acc0 + acc1) + (acc2 + acc3);                        \
            float so = __shfl_xor(sv, 32);                                   \
            z = (sv + so) + (XCQ);                                           \
        }                                                                    \
        const float term1 = __builtin_fmaf(sj, 1.0f - hj, hj);               \
        float e  = __builtin_amdgcn_exp2f(z);     /* e^{2z}, prescaled */    \
        float rr = __builtin_amdgcn_rcpf(e + 1.0f);                          \
        hj = __builtin_fmaf(nsj2, rr, term1);     /* h + s*(tanh-h) */       \
        hbuf[WB][mycol] = (_Float16)hj;  /* dup lanes same value: benign */  \
        LGKM_BARRIER();                                                      \
    } while (0)

#define STAGE_AND_PROJECT()                                                  \
    do {                                                                     \
        *(half8*)&xstage[Mts][c16][ms][0] = cvt8(xpreA, xpreB);              \
        __syncthreads();                                                     \
        _Pragma("unroll")                                                    \
        for (int Mt = 0; Mt < 2; ++Mt) {                                     \
            half8 ax[4];                                                     \
            _Pragma("unroll")                                                \
            for (int ks = 0; ks < 4; ++ks)                                   \
                ax[ks] = *(const half8*)&xstage[Mt][4*ks + q][n][0];         \
            f32x4 pa[2];                                                     \
            _Pragma("unroll")                                                \
            for (int t = 0; t < 2; ++t)                                      \
                pa[t] = (f32x4){biasv[t], biasv[t], biasv[t], biasv[t]};     \
            _Pragma("unroll")                                                \
            for (int ks = 0; ks < 4; ++ks)                                   \
                _Pragma("unroll")                                            \
                for (int t = 0; t < 2; ++t)                                  \
                    pa[t] = __builtin_amdgcn_mfma_f32_16x16x32_f16(          \
                        ax[ks], bx[t][ks], pa[t], 0, 0, 0);                  \
            _Pragma("unroll")                                                \
            for (int r = 0; r < 4; ++r) {                                    \
                union { _Float16 h[2]; unsigned u; } pk;                     \
                pk.h[0] = (_Float16)pa[0][r];                                \
                pk.h[1] = (_Float16)pa[1][r];                                \
                *(unsigned*)&pchunk[16*Mt + 4*q + r][g][n][0] = pk.u;        \
            }                                                                \
        }                                                                    \
        __syncthreads();                                                     \
    } while (0)

#define PREFETCH_NEXT()                                                      \
    do {                                                                     \
        const int nc = (tc + 32 < T) ? tc + 32 : tc;                         \
        int tg = nc + t_u; if (tg > T - 1) tg = T - 1;                       \
        const float4* src = (const float4*)(xb + (size_t)tg * 128 + 8*c16);  \
        xpreA = src[0]; xpreB = src[1];                                      \
    } while (0)

#define XCQ_LOAD(TS)                                                         \
    float xcq;                                                               \
    {                                                                        \
        unsigned d = *(const unsigned*)&pchunk[TS][pg][n][0];                \
        d >>= shamt;                                                         \
        union { unsigned u; _Float16 h[2]; } uu; uu.u = d;                   \
        xcq = (float)uu.h[0];                                                \
    }

    if (L == 2) {
        for (int tc = 0; tc < T; tc += 32) {
            STAGE_AND_PROJECT();
            PREFETCH_NEXT();
            const int tlen = (T - tc < 32) ? (T - tc) : 32;
#pragma unroll 2
            for (int ts = 0; ts < tlen; ++ts) {
                XCQ_LOAD(ts);
                LAYER(0, 1, xcq);   // layer 1: buf0 -> buf1
                LAYER(1, 0, xcq);   // layer 2: buf1 -> buf0
            }
        }
    } else {
        int hb = 0;
        for (int tc = 0; tc < T; tc += 32) {
            STAGE_AND_PROJECT();
            PREFETCH_NEXT();
            const int tlen = (T - tc < 32) ? (T - tc) : 32;
            for (int ts = 0; ts < tlen; ++ts) {
                XCQ_LOAD(ts);
                for (int l = 0; l < L; ++l) {
                    if (hb == 0) LAYER(0, 1, xcq);
                    else         LAYER(1, 0, xcq);
                    hb ^= 1;
                }
            }
        }
    }
#undef LAYER
#undef STAGE_AND_PROJECT
#undef PREFETCH_NEXT
#undef XCQ_LOAD

    if (q < 2)
        out[(size_t)b * 256 + mycol] = hj;
}

extern "C" void kernel_launch(void* const* d_in, const int* in_sizes, int n_in,
                              void* d_out, int out_size, void* d_ws, size_t ws_size,
                              hipStream_t stream) {
    const float* x     = (const float*)d_in[0];
    const float* W_in  = (const float*)d_in[1];
    const float* b_in  = (const float*)d_in[2];
    const float* W_rec = (const float*)d_in[3];
    const float* b_rec = (const float*)d_in[4];
    const float* tau   = (const float*)d_in[5];
    const int*   numl  = (const int*)d_in[6];

    const int H = in_sizes[2];            // 256
    const int I = in_sizes[1] / H;        // 128
    const int B = out_size / H;           // 64
    const int T = in_sizes[0] / (B * I);  // 4096

    ltc_fused<<<B, 512, 0, stream>>>(x, W_in, b_in, W_rec, b_rec, tau,
                                     numl, (float*)d_out, T);
}